// Round 7
// baseline (1037.946 us; speedup 1.0000x reference)
//
#include <hip/hip_runtime.h>

// MSDNet on gfx950 — round 7: channels-last fp16 + v_dot2_f32_f16.
// Theory (R1/R5/R6): the wall is wave-VMEM instruction throughput (~7-8
// cyc/instr); 2B-aligned h8 taps get split into ushort loads (16.7k
// instr/CU, same as R1's scalar fp32 -> same ~50-60 us). Fix: feats in
// [b][y][x][32ch] fp16 (64B/px, aligned): every tap is an ALIGNED dwordx4
// of 8 channels; 9 tap addresses computed once, channel-octet loop uses
// +16B immediate offsets. Channel contraction via v_dot2_f32_f16 (fp16
// pairs, fp32 acc): no cvts, 4x fewer VALU ops. Weights pre-packed to
// fp16 pairs (uniform -> scalar loads). Depth 29 fuses 1x1 conv + affine.

#define MSD_DEPTH 30
#define NB 4
#define IH 512
#define IW 512
#define HALO 16
#define WC (IW + 2 * HALO) /* 544 */
#define HC (IH + 2 * HALO) /* 544 */
#define CP 32              /* padded channel count (fp16) -> 64 B per px */
#define ROWSTRIDE ((size_t)WC * CP)
#define BSTRIDE ((size_t)HC * WC * CP)
#define FEATS_ELEMS ((size_t)NB * BSTRIDE)
#define WPK_OFF_BYTES ((FEATS_ELEMS * 2 + 255) & ~(size_t)255)
#define NPIX (NB * IH * IW) /* 1048576 */

typedef _Float16 h2 __attribute__((ext_vector_type(2)));
typedef unsigned int uint;

__device__ __forceinline__ float dot2(uint f, uint w, float acc) {
#if __has_builtin(__builtin_amdgcn_fdot2)
    return __builtin_amdgcn_fdot2(__builtin_bit_cast(h2, f),
                                  __builtin_bit_cast(h2, w), acc, false);
#else
    h2 ff = __builtin_bit_cast(h2, f), ww = __builtin_bit_cast(h2, w);
    return acc + (float)ff[0] * (float)ww[0] + (float)ff[1] * (float)ww[1];
#endif
}

// ---------------------------------------------------------------------------
// Pack Wmsd (fp32) -> wpk fp16-pair dwords, layout [30][4 octets][9 taps][4
// pairs]; channels >= n_in get weight 0 (poison channels are finite -> x0=0).
// Also pack convW[0..29] into cpk[16] pairs (pair 15 zeroed; convW[30] is
// applied separately in fp32).
__global__ __launch_bounds__(256) void pack_weights(const float* __restrict__ Wmsd,
                                                    const float* __restrict__ convW,
                                                    uint* __restrict__ wpk_u,
                                                    uint* __restrict__ cpk) {
    int idx = blockIdx.x * 256 + threadIdx.x;
    if (idx < MSD_DEPTH * 4 * 9 * 4) {
        int p = idx & 3;
        int t = (idx >> 2) % 9;
        int o = (idx / 36) & 3;
        int I = idx / 144;
        int c0 = o * 8 + p * 2, c1 = c0 + 1, NC = I + 1;
        float w0 = (c0 < NC) ? Wmsd[((size_t)I * MSD_DEPTH + c0) * 9 + t] : 0.f;
        float w1 = (c1 < NC) ? Wmsd[((size_t)I * MSD_DEPTH + c1) * 9 + t] : 0.f;
        h2 pk;
        pk[0] = (_Float16)w0;
        pk[1] = (_Float16)w1;
        wpk_u[idx] = __builtin_bit_cast(uint, pk);
    }
    if (idx < 16) {
        int c0 = idx * 2, c1 = c0 + 1;
        float w0 = (c0 <= 29) ? convW[c0] : 0.f;
        float w1 = (c1 <= 29) ? convW[c1] : 0.f;
        h2 pk;
        pk[0] = (_Float16)w0;
        pk[1] = (_Float16)w1;
        cpk[idx] = __builtin_bit_cast(uint, pk);
    }
}

// ---------------------------------------------------------------------------
// Zero ALL 32 channels of every spatial-halo pixel (ws is re-poisoned each
// call). Interior unwritten channels are poison-finite and get zero weights.
__global__ __launch_bounds__(256) void zero_halo_cl(_Float16* __restrict__ feats) {
    const int per = WC * HC - IW * IH; // 33792 halo px per batch
    int idx = blockIdx.x * 256 + threadIdx.x;
    if (idx >= per * NB) return;
    int b = idx / per;
    int rem = idx - b * per;
    int r, c;
    if (rem < HALO * WC) {
        r = rem / WC; c = rem % WC;
    } else if (rem < 2 * HALO * WC) {
        int t = rem - HALO * WC;
        r = (IH + HALO) + t / WC; c = t % WC;
    } else {
        int t = rem - 2 * HALO * WC;
        r = HALO + t / (2 * HALO);
        int u = t % (2 * HALO);
        c = (u < HALO) ? u : (IW + u);
    }
    uint4* q = (uint4*)(feats + (size_t)b * BSTRIDE + ((size_t)r * WC + c) * CP);
    uint4 z = {0, 0, 0, 0};
    q[0] = z; q[1] = z; q[2] = z; q[3] = z;
}

// ---------------------------------------------------------------------------
// Channel 0 = fp16(x * sin_w + sin_b).
__global__ __launch_bounds__(256) void scale_in_cl(const float* __restrict__ x,
                                                   _Float16* __restrict__ feats,
                                                   const float* __restrict__ sw,
                                                   const float* __restrict__ sb) {
    int idx = blockIdx.x * 256 + threadIdx.x; // 0..NPIX-1
    int b = idx >> 18;
    int y = (idx >> 9) & 511;
    int xx = idx & 511;
    float v = x[idx] * sw[0] + sb[0];
    feats[(size_t)b * BSTRIDE + (size_t)(y + HALO) * ROWSTRIDE + (size_t)(xx + HALO) * CP] =
        (_Float16)v;
}

// ---------------------------------------------------------------------------
// Depth kernel I, channels-last: 1 px per thread, tile 64x4 per block.
template <int I>
__global__ __launch_bounds__(256) void depth_cl(_Float16* __restrict__ feats,
                                                const uint4* __restrict__ wpk,
                                                const uint* __restrict__ cpk,
                                                const float* __restrict__ bias,
                                                const float* __restrict__ convW,
                                                const float* __restrict__ convB,
                                                const float* __restrict__ soutw,
                                                const float* __restrict__ soutb,
                                                float* __restrict__ out) {
    constexpr int D = (I % 10) + 1;
    constexpr int NC = I + 1;
    constexpr int OCT = (NC + 7) / 8;
    constexpr bool LAST = (I == MSD_DEPTH - 1);

    const int tid = threadIdx.x;
    const int bid = blockIdx.x; // 4096 blocks
    // XCD band swizzle (validated R4-R6): xcd = bid&7; 2 XCDs per image;
    // each XCD owns a contiguous 256-row band.
    const int xcd = bid & 7;
    const int k = bid >> 3;                    // 0..511
    const int b = xcd >> 1;
    const int ty = (xcd & 1) * 64 + (k >> 3);  // 0..127 (4-row tiles)
    const int tx = k & 7;                      // 0..7 (64-px col tiles)
    const int gx = tx * 64 + (tid & 63);
    const int gy = ty * 4 + (tid >> 6);

    _Float16* px = feats + (size_t)b * BSTRIDE + (size_t)(gy + HALO) * ROWSTRIDE +
                   (size_t)(gx + HALO) * CP;

    // 9 tap base pointers (aligned 64B); octet loop uses +16B imm offsets.
    const uint4* tp[9];
#pragma unroll
    for (int dy = -1; dy <= 1; ++dy)
#pragma unroll
        for (int dx = -1; dx <= 1; ++dx)
            tp[(dy + 1) * 3 + (dx + 1)] = (const uint4*)(px + (dy * WC + dx) * D * CP);

    float acc = 0.f, ydot = 0.f;
#pragma unroll
    for (int o = 0; o < OCT; ++o) {
        uint4 f[9];
#pragma unroll
        for (int t = 0; t < 9; ++t) f[t] = tp[t][o]; // 9 aligned dwordx4 in flight
        const uint4* wq = wpk + ((size_t)I * 4 + o) * 9; // uniform -> s_load
#pragma unroll
        for (int t = 0; t < 9; ++t) {
            uint4 W = wq[t];
            acc = dot2(f[t].x, W.x, acc);
            acc = dot2(f[t].y, W.y, acc);
            acc = dot2(f[t].z, W.z, acc);
            acc = dot2(f[t].w, W.w, acc);
        }
        if (LAST) { // 1x1-conv dot with the center tap's channels
            ydot = dot2(f[4].x, cpk[o * 4 + 0], ydot);
            ydot = dot2(f[4].y, cpk[o * 4 + 1], ydot);
            ydot = dot2(f[4].z, cpk[o * 4 + 2], ydot);
            ydot = dot2(f[4].w, cpk[o * 4 + 3], ydot);
        }
    }

    float h = acc + bias[I];
    h = h > 0.f ? h : 0.f;
    if (!LAST) {
        px[NC] = (_Float16)h; // write channel I+1
    } else {
        float y = ydot + convW[MSD_DEPTH] * h + convB[0];
        y = y * soutw[0] + soutb[0];
        out[((size_t)b * IH + gy) * IW + gx] = y;
    }
}

// ---------------------------------------------------------------------------
extern "C" void kernel_launch(void* const* d_in, const int* in_sizes, int n_in,
                              void* d_out, int out_size, void* d_ws, size_t ws_size,
                              hipStream_t stream) {
    const float* x     = (const float*)d_in[0];
    const float* Wmsd  = (const float*)d_in[1];
    const float* bias  = (const float*)d_in[2];
    const float* convW = (const float*)d_in[3];
    const float* convB = (const float*)d_in[4];
    const float* sinw  = (const float*)d_in[5];
    const float* sinb  = (const float*)d_in[6];
    const float* soutw = (const float*)d_in[7];
    const float* soutb = (const float*)d_in[8];
    float* out = (float*)d_out;

    _Float16* feats = (_Float16*)d_ws;
    uint* wpk_u = (uint*)((char*)d_ws + WPK_OFF_BYTES);
    uint* cpk = wpk_u + MSD_DEPTH * 4 * 9 * 4;
    const uint4* wpk_q = (const uint4*)wpk_u;

    pack_weights<<<17, 256, 0, stream>>>(Wmsd, convW, wpk_u, cpk);

    const int halo_total = (WC * HC - IW * IH) * NB; // 135168
    zero_halo_cl<<<(halo_total + 255) / 256, 256, 0, stream>>>(feats);

    scale_in_cl<<<NPIX / 256, 256, 0, stream>>>(x, feats, sinw, sinb);

#define LNCH(I)                                                                \
    depth_cl<I><<<4096, 256, 0, stream>>>(feats, wpk_q, cpk, bias, convW,      \
                                          convB, soutw, soutb, out);
    LNCH(0)  LNCH(1)  LNCH(2)  LNCH(3)  LNCH(4)
    LNCH(5)  LNCH(6)  LNCH(7)  LNCH(8)  LNCH(9)
    LNCH(10) LNCH(11) LNCH(12) LNCH(13) LNCH(14)
    LNCH(15) LNCH(16) LNCH(17) LNCH(18) LNCH(19)
    LNCH(20) LNCH(21) LNCH(22) LNCH(23) LNCH(24)
    LNCH(25) LNCH(26) LNCH(27) LNCH(28) LNCH(29)
#undef LNCH
}

// Round 8
// 507.110 us; speedup vs baseline: 2.0468x; 2.0468x over previous
//
#include <hip/hip_runtime.h>

// MSDNet on gfx950 — round 8: NCHW fp16, ALIGNED octet loads + register shifts.
// Unified cost model from R1-R7: cost/CU = max(~7cyc * VMEM_instr, ~1cyc *
// L1_lines, VALU, HBM). R5 lost on split unaligned loads (instr), R7 lost on
// 64B-strided taps (lines). This round: one wave = one 512-px row; per plane
// 9 (15 if D>8) ALIGNED dwordx4 loads; horizontal +-D windows built in
// registers (v_alignbit funnel for odd D, dword select for even D); fp32
// accumulate via the fma(fpext(f16), f32) -> v_fma_mix pattern. Explicit
// 2-deep plane double-buffer; __launch_bounds__(128,2) gives VGPR room.
// ws: 30 zero-halo-padded fp16 planes [c][b][y][x], HALO=16. Depth 29 fuses
// the 1x1 conv + output affine; h29 never materialized.

#define MSD_DEPTH 30
#define NB 4
#define IH 512
#define IW 512
#define HALO 16
#define WPp (IW + 2 * HALO) /* 544 px per row */
#define HPp (IH + 2 * HALO) /* 544 rows */
#define PLANE_E ((size_t)WPp * HPp)       /* elems per subplane */
#define CSTR ((size_t)NB * PLANE_E)       /* plane stride (elems) */
#define NPIX (NB * IH * IW)

typedef _Float16 h2 __attribute__((ext_vector_type(2)));
typedef float f4 __attribute__((ext_vector_type(4)));
typedef unsigned int u32;

// ---------------------------------------------------------------------------
// Zero the halo ring of all 120 subplanes, 8-px (16B) aligned strips.
// Per subplane: 2*16 full rows (2176 strips) + 512 rows * 4 side strips.
#define STRIPS_PER_SUB (2176 + 512 * 4) /* 4224 */
__global__ __launch_bounds__(256) void zero_halo_kernel(_Float16* __restrict__ feats) {
    int idx = blockIdx.x * 256 + threadIdx.x;
    const int total = STRIPS_PER_SUB * MSD_DEPTH * NB;
    if (idx >= total) return;
    int sub = idx / STRIPS_PER_SUB;
    int s = idx - sub * STRIPS_PER_SUB;
    int r, cpx;
    if (s < 2176) {                 // top/bottom full rows
        int rr = s / 68;            // 68 strips per 544-px row
        cpx = (s - rr * 68) * 8;
        r = (rr < 16) ? rr : (IH + HALO) + (rr - 16);
    } else {                        // side strips of interior rows
        int t = s - 2176;
        r = HALO + t / 4;
        int j = t & 3;
        cpx = (j < 2) ? j * 8 : (IW + HALO) + (j - 2) * 8;
    }
    uint4 z = {0, 0, 0, 0};
    *(uint4*)(feats + (size_t)sub * PLANE_E + (size_t)r * WPp + cpx) = z;
}

// ---------------------------------------------------------------------------
__global__ __launch_bounds__(256) void scale_in_kernel(const float* __restrict__ x,
                                                       _Float16* __restrict__ feats,
                                                       const float* __restrict__ sw,
                                                       const float* __restrict__ sb) {
    int s = blockIdx.x * 256 + threadIdx.x; // 8-px strip
    int idx = s * 8;
    int b = idx >> 18;
    int y = (idx >> 9) & 511;
    int xx = idx & 511;
    const float sws = sw[0], sbs = sb[0];
    _Float16 v[8];
#pragma unroll
    for (int j = 0; j < 8; ++j) v[j] = (_Float16)(x[idx + j] * sws + sbs);
    *(uint4*)(feats + (size_t)b * PLANE_E + (size_t)(y + HALO) * WPp + (xx + HALO)) =
        *(uint4*)v;
}

// ---------------------------------------------------------------------------
// Window extraction: 16B window starting at byte SB of the 80B concat cd[20].
template <int SB>
__device__ __forceinline__ void win(const u32* cd, u32 w[4]) {
    constexpr int q = SB >> 2;
    if constexpr ((SB & 2) != 0) {
#pragma unroll
        for (int i = 0; i < 4; ++i)
            w[i] = __builtin_amdgcn_alignbit(cd[q + i + 1], cd[q + i], 16);
    } else {
#pragma unroll
        for (int i = 0; i < 4; ++i) w[i] = cd[q + i];
    }
}

// acc[0..7] += wt * fp16px(w[0..3])  (v_fma_mix pattern: fma(fpext, f32, f32))
__device__ __forceinline__ void fma8(float* acc, const u32* w, float wt) {
#pragma unroll
    for (int i = 0; i < 4; ++i) {
        h2 h = __builtin_bit_cast(h2, w[i]);
        acc[2 * i]     = fmaf((float)h[0], wt, acc[2 * i]);
        acc[2 * i + 1] = fmaf((float)h[1], wt, acc[2 * i + 1]);
    }
}

// ---------------------------------------------------------------------------
template <int I>
__global__ __launch_bounds__(128, 2) void depth_kernel(_Float16* __restrict__ feats,
                                                       const float* __restrict__ Wmsd,
                                                       const float* __restrict__ bias,
                                                       const float* __restrict__ convW,
                                                       const float* __restrict__ convB,
                                                       const float* __restrict__ soutw,
                                                       const float* __restrict__ soutb,
                                                       float* __restrict__ out) {
    constexpr int D = (I % 10) + 1;
    constexpr int NC = I + 1;
    constexpr bool LAST = (I == MSD_DEPTH - 1);
    constexpr bool WIDE = (D > 8);
    constexpr int NOCT = WIDE ? 15 : 9;

    const int tid = threadIdx.x;
    const int bid = blockIdx.x; // 1024 blocks, 128 threads (2 rows)
    // XCD band swizzle (validated R4-R7): xcd = bid&7; 2 XCDs per image;
    // each XCD owns a contiguous 256-row band of one image.
    const int xcd = bid & 7;
    const int k = bid >> 3;                       // 0..127
    const int b = xcd >> 1;
    const int y = (xcd & 1) * 256 + k * 2 + (tid >> 6);
    const int lane = tid & 63;

    const size_t rowoff = (size_t)(y + HALO) * WPp + HALO + lane * 8; // 16B-aligned
    const _Float16* const p0 = feats + (size_t)b * PLANE_E + rowoff;

    float acc[8], ydot[8];
#pragma unroll
    for (int j = 0; j < 8; ++j) { acc[j] = 0.f; ydot[j] = 0.f; }

    const float* const wrb = Wmsd + (size_t)I * (MSD_DEPTH * 9);

    uint4 A[NOCT], B[NOCT];

    auto load_plane = [&](uint4* o, const _Float16* pc) {
#pragma unroll
        for (int r = 0; r < 3; ++r) {
            const _Float16* rp = pc + (ptrdiff_t)(r - 1) * D * WPp;
            o[r * 3 + 0] = *(const uint4*)(rp - 8);
            o[r * 3 + 1] = *(const uint4*)(rp);
            o[r * 3 + 2] = *(const uint4*)(rp + 8);
            if constexpr (WIDE) {
                o[9 + r * 2 + 0] = *(const uint4*)(rp - 16);
                o[9 + r * 2 + 1] = *(const uint4*)(rp + 16);
            }
        }
    };

    auto compute = [&](const uint4* o, int c) {
        const float* wk = wrb + c * 9; // uniform -> s_load
        const float cw = LAST ? convW[c] : 0.f;
#pragma unroll
        for (int r = 0; r < 3; ++r) {
            u32 cd[20];
            *(uint4*)&cd[4] = o[r * 3 + 0];
            *(uint4*)&cd[8] = o[r * 3 + 1];
            *(uint4*)&cd[12] = o[r * 3 + 2];
            if constexpr (WIDE) {
                *(uint4*)&cd[0] = o[9 + r * 2 + 0];
                *(uint4*)&cd[16] = o[9 + r * 2 + 1];
            }
            u32 wl[4], wr_[4];
            win<32 - 2 * D>(cd, wl);
            win<32 + 2 * D>(cd, wr_);
            fma8(acc, wl, wk[r * 3 + 0]);
            fma8(acc, &cd[8], wk[r * 3 + 1]);
            fma8(acc, wr_, wk[r * 3 + 2]);
            if (LAST && r == 1) fma8(ydot, &cd[8], cw);
        }
    };

    // 2-deep software pipeline over planes.
    load_plane(A, p0);
    int c = 0;
    for (; c + 2 <= NC; c += 2) {
        load_plane(B, p0 + (size_t)(c + 1) * CSTR);
        compute(A, c);
        if (c + 2 < NC) load_plane(A, p0 + (size_t)(c + 2) * CSTR);
        compute(B, c + 1);
    }
    if (c < NC) compute(A, c);

    const float b0 = bias[I];
    if (!LAST) {
        _Float16 hv[8];
#pragma unroll
        for (int j = 0; j < 8; ++j) {
            float h = acc[j] + b0;
            hv[j] = (_Float16)(h > 0.f ? h : 0.f);
        }
        *(uint4*)(feats + (size_t)NC * CSTR + (size_t)b * PLANE_E + rowoff) = *(uint4*)hv;
    } else {
        const float cw29 = convW[MSD_DEPTH];
        const float cb = convB[0], ow = soutw[0], ob = soutb[0];
        float* q = out + ((size_t)b * IH + y) * IW + lane * 8;
        f4 y0, y1;
#pragma unroll
        for (int j = 0; j < 8; ++j) {
            float h = acc[j] + b0;
            h = h > 0.f ? h : 0.f;
            float yv = ydot[j] + cw29 * h + cb;
            yv = yv * ow + ob;
            if (j < 4) y0[j] = yv; else y1[j - 4] = yv;
        }
        *(f4*)q = y0;
        *(f4*)(q + 4) = y1;
    }
}

// ---------------------------------------------------------------------------
extern "C" void kernel_launch(void* const* d_in, const int* in_sizes, int n_in,
                              void* d_out, int out_size, void* d_ws, size_t ws_size,
                              hipStream_t stream) {
    const float* x     = (const float*)d_in[0];
    const float* Wmsd  = (const float*)d_in[1];
    const float* bias  = (const float*)d_in[2];
    const float* convW = (const float*)d_in[3];
    const float* convB = (const float*)d_in[4];
    const float* sinw  = (const float*)d_in[5];
    const float* sinb  = (const float*)d_in[6];
    const float* soutw = (const float*)d_in[7];
    const float* soutb = (const float*)d_in[8];
    float* out = (float*)d_out;
    _Float16* feats = (_Float16*)d_ws;

    const int strips = STRIPS_PER_SUB * MSD_DEPTH * NB; // 506880
    zero_halo_kernel<<<(strips + 255) / 256, 256, 0, stream>>>(feats);

    scale_in_kernel<<<NPIX / 8 / 256, 256, 0, stream>>>(x, feats, sinw, sinb);

#define LNCH(I) depth_kernel<I><<<1024, 128, 0, stream>>>(feats, Wmsd, bias, convW, convB, soutw, soutb, out);
    LNCH(0)  LNCH(1)  LNCH(2)  LNCH(3)  LNCH(4)
    LNCH(5)  LNCH(6)  LNCH(7)  LNCH(8)  LNCH(9)
    LNCH(10) LNCH(11) LNCH(12) LNCH(13) LNCH(14)
    LNCH(15) LNCH(16) LNCH(17) LNCH(18) LNCH(19)
    LNCH(20) LNCH(21) LNCH(22) LNCH(23) LNCH(24)
    LNCH(25) LNCH(26) LNCH(27) LNCH(28) LNCH(29)
#undef LNCH
}